// Round 12
// baseline (308.757 us; speedup 1.0000x reference)
//
#include <hip/hip_runtime.h>

typedef _Float16 half8 __attribute__((ext_vector_type(8)));
typedef float f32x4 __attribute__((ext_vector_type(4)));

#define N_PTS   32768
#define DIMS    64
#define K_CODES 8192

// ---- d_out layout (floats, reference return order) ----
#define OUT_ZQ      0          // 32768*64
#define OUT_IDX     2097152    // 32768 (as float)
#define OUT_LOSS    2129920    // 1
#define OUT_NEWEMB  2129921    // 8192*64
#define OUT_NCS     2654209    // 8192
#define OUT_NEWEMA  2662401    // 8192*64

// ---- scratch inside the z_q region of d_out ----
// All consumed BEFORE scatter_light writes z_q: ehi/elo/ensc by argmin,
// val/idx partials by combine, fixlist by fixup. sorted/offsets now live in
// d_ws (r4/5 crash class eliminated).
#define SC_EHI      0          // 262144 floats
#define SC_ELO      262144     // 262144
#define SC_ENSC     524288     // 8192
#define SC_VAL1     532480     // 8*32768
#define SC_IDX1     794624     // 8*32768 (int)
#define SC_VAL2     1056768    // 8*32768
#define SC_FIXLIST  1318912    // 4096 (int)
// ends 1323008 < 2097152

// ---- d_ws layout (floats) ----
#define WS_COUNTS   0          // 8192
#define WS_CURSOR   8192       // 8192 (int)
#define WS_LOSS     16384
#define WS_NSUM     16385
#define WS_FIXCNT   16386      // int (+1 pad)
#define WS_ZERO_BYTES (16388u * 4u)
#define WS_NCS      16388      // 8192
#define WS_ENORM    24580      // 8192
#define WS_IDX      32772      // 32768 (int)
#define WS_SORTED   65540      // 32768 (int)
#define WS_OFFSETS  98308      // 8192 (int)
// ends 106500 floats (~426 KB)

#define MARGIN_SCALED 16.0f

__device__ inline void gld16(const void* g, void* l) {
    __builtin_amdgcn_global_load_lds((const __attribute__((address_space(1))) unsigned*)g,
                                     (__attribute__((address_space(3))) unsigned*)l, 16, 0, 0);
}
__device__ inline void gld4(const void* g, void* l) {
    __builtin_amdgcn_global_load_lds((const __attribute__((address_space(1))) unsigned*)g,
                                     (__attribute__((address_space(3))) unsigned*)l, 4, 0, 0);
}

// ============================================================
// K0: split codebook into f16 hi/lo (x256), 16B-chunk-swizzled; norms.
// ============================================================
__global__ __launch_bounds__(256) void esplit_kernel(const float* __restrict__ emb,
                                                     float4* __restrict__ ehi4,
                                                     float4* __restrict__ elo4,
                                                     float* __restrict__ ensc,
                                                     float* __restrict__ enorm) {
    int k = blockIdx.x * 256 + threadIdx.x;
    const float4* e4 = reinterpret_cast<const float4*>(emb + (size_t)k * DIMS);
    float vals[64];
    float sum = 0.0f;
#pragma unroll
    for (int i = 0; i < 16; ++i) {
        float4 v = e4[i];
        vals[i*4+0] = v.x; vals[i*4+1] = v.y; vals[i*4+2] = v.z; vals[i*4+3] = v.w;
        sum = fmaf(v.x, v.x, sum); sum = fmaf(v.y, v.y, sum);
        sum = fmaf(v.z, v.z, sum); sum = fmaf(v.w, v.w, sum);
    }
    enorm[k] = sum;
    ensc[k]  = 65536.0f * sum;
#pragma unroll
    for (int c = 0; c < 8; ++c) {
        union { _Float16 h[8]; float4 v; } uh, ul;
#pragma unroll
        for (int j = 0; j < 8; ++j) {
            float X = 256.0f * vals[c*8+j];
            _Float16 hh = (_Float16)X;
            uh.h[j] = hh;
            ul.h[j] = (_Float16)(X - (float)hh);
        }
        int cc = c ^ (k & 7);
        ehi4[(size_t)k*8 + cc] = uh.v;
        elo4[(size_t)k*8 + cc] = ul.v;
    }
}

// ============================================================
// K1: MFMA argmin, 2-subtile waves (32 rows/wave, 128 rows/block).
// r10 counters: VGPR=56, no spill, but occupancy stuck at 33% -- LDS (33KB ->
// 4 blocks/CU) and grid (1024 = exactly 4/CU) were the binding limits.
// This round: chunk 64->32 codes (LDS 16.6KB) + 8 code-splits (grid 2048
// = 8 blocks/CU). Staging = exactly 1 gld16/thread/buffer per chunk.
// Plain __launch_bounds__(256) -- never force min-waves (r6/r8 spills).
// ============================================================
__global__ __launch_bounds__(256) void argmin_mfma(const float* __restrict__ z,
                                                   const char* __restrict__ ehi_g,
                                                   const char* __restrict__ elo_g,
                                                   const float* __restrict__ ensc_g,
                                                   float* __restrict__ val1,
                                                   int* __restrict__ idx1,
                                                   float* __restrict__ val2) {
    __shared__ __align__(16) char ebuf[2][2][4096];   // [buf][hi/lo][32 codes * 128B]
    __shared__ float enb[2][32];

    const int tid = threadIdx.x;
    const int w   = tid >> 6;
    const int l   = tid & 63;
    const int l15 = l & 15;
    const int l4  = l >> 4;
    const int bid = blockIdx.x;
    const int rowbase = (bid >> 3) * 128 + w * 32;
    const int c0      = (bid & 7) * 1024;

    half8 ahi[2][2], alo[2][2];
#pragma unroll
    for (int s = 0; s < 2; ++s) {
        const float* zp = z + (size_t)(rowbase + s*16 + l15) * DIMS + l4 * 8;
#pragma unroll
        for (int ks = 0; ks < 2; ++ks) {
            float4 z0 = *reinterpret_cast<const float4*>(zp + ks*32);
            float4 z1 = *reinterpret_cast<const float4*>(zp + ks*32 + 4);
            float xv[8] = {z0.x, z0.y, z0.z, z0.w, z1.x, z1.y, z1.z, z1.w};
            half8 h, lo;
#pragma unroll
            for (int j = 0; j < 8; ++j) {
                float X = -512.0f * xv[j];
                _Float16 hh = (_Float16)X;
                h[j]  = hh;
                lo[j] = (_Float16)(X - (float)hh);
            }
            ahi[s][ks] = h; alo[s][ks] = lo;
        }
    }

    float b1[8], b2[8]; int i1[8];
#pragma unroll
    for (int r = 0; r < 8; ++r) { b1[r] = 3.4e38f; b2[r] = 3.4e38f; i1[r] = 0; }

    int rdoff[2];
#pragma unroll
    for (int ks = 0; ks < 2; ++ks)
        rdoff[ks] = l15 * 128 + (((ks*4 + l4) ^ (l15 & 7)) * 16);

    {   // stage chunk 0 (32 codes, 4096 B per hi/lo)
        const size_t gb = (size_t)c0 * 128;
        gld16(ehi_g + gb + tid*16, &ebuf[0][0][0] + w*1024);
        gld16(elo_g + gb + tid*16, &ebuf[0][1][0] + w*1024);
        if (w == 0 && l < 32) gld4(ensc_g + c0 + l, &enb[0][0]);
    }
    __syncthreads();

    int b = 0;
    for (int ch = 0; ch < 32; ++ch) {
        if (ch < 31) {
            const size_t gb = (size_t)(c0 + (ch+1)*32) * 128;
            gld16(ehi_g + gb + tid*16, &ebuf[b^1][0][0] + w*1024);
            gld16(elo_g + gb + tid*16, &ebuf[b^1][1][0] + w*1024);
            if (w == 0 && l < 32) gld4(ensc_g + c0 + (ch+1)*32 + l, &enb[b^1][0]);
        }
        const char* bhbase = &ebuf[b][0][0];
        const char* blbase = &ebuf[b][1][0];
#pragma unroll
        for (int t = 0; t < 2; ++t) {
            float en = enb[b][t*16 + l15];
            f32x4 envec = (f32x4){en, en, en, en};
            half8 bh[2], bl[2];
#pragma unroll
            for (int ks = 0; ks < 2; ++ks) {
                bh[ks] = *reinterpret_cast<const half8*>(bhbase + t*2048 + rdoff[ks]);
                bl[ks] = *reinterpret_cast<const half8*>(blbase + t*2048 + rdoff[ks]);
            }
            f32x4 acc[2];
            __builtin_amdgcn_s_setprio(1);
#pragma unroll
            for (int s = 0; s < 2; ++s)
                acc[s] = __builtin_amdgcn_mfma_f32_16x16x32_f16(ahi[s][0], bh[0], envec, 0, 0, 0);
#pragma unroll
            for (int s = 0; s < 2; ++s)
                acc[s] = __builtin_amdgcn_mfma_f32_16x16x32_f16(ahi[s][0], bl[0], acc[s], 0, 0, 0);
#pragma unroll
            for (int s = 0; s < 2; ++s)
                acc[s] = __builtin_amdgcn_mfma_f32_16x16x32_f16(alo[s][0], bh[0], acc[s], 0, 0, 0);
#pragma unroll
            for (int s = 0; s < 2; ++s)
                acc[s] = __builtin_amdgcn_mfma_f32_16x16x32_f16(ahi[s][1], bh[1], acc[s], 0, 0, 0);
#pragma unroll
            for (int s = 0; s < 2; ++s)
                acc[s] = __builtin_amdgcn_mfma_f32_16x16x32_f16(ahi[s][1], bl[1], acc[s], 0, 0, 0);
#pragma unroll
            for (int s = 0; s < 2; ++s)
                acc[s] = __builtin_amdgcn_mfma_f32_16x16x32_f16(alo[s][1], bh[1], acc[s], 0, 0, 0);
            __builtin_amdgcn_s_setprio(0);

            const int code = c0 + ch*32 + t*16 + l15;
#pragma unroll
            for (int s = 0; s < 2; ++s) {
#pragma unroll
                for (int j = 0; j < 4; ++j) {
                    const int r = s*4 + j;
                    float v = acc[s][j];
                    float nb2;
                    asm("v_med3_f32 %0, %1, %2, %3"
                        : "=v"(nb2) : "v"(b1[r]), "v"(b2[r]), "v"(v));
                    b2[r] = nb2;
                    bool c = v < b1[r];
                    b1[r] = c ? v : b1[r];
                    i1[r] = c ? code : i1[r];
                }
            }
        }
        __syncthreads();
        b ^= 1;
    }

#pragma unroll
    for (int m = 1; m < 16; m <<= 1) {
#pragma unroll
        for (int r = 0; r < 8; ++r) {
            float ob1 = __shfl_xor(b1[r], m, 64);
            int   oi1 = __shfl_xor(i1[r], m, 64);
            float ob2 = __shfl_xor(b2[r], m, 64);
            float nb2 = fminf(fminf(b2[r], ob2), fmaxf(b1[r], ob1));
            bool take = (ob1 < b1[r]) || (ob1 == b1[r] && oi1 < i1[r]);
            b1[r] = take ? ob1 : b1[r];
            i1[r] = take ? oi1 : i1[r];
            b2[r] = nb2;
        }
    }
    if (l15 == 0) {
        const int cs = bid & 7;
#pragma unroll
        for (int s = 0; s < 2; ++s)
#pragma unroll
            for (int j = 0; j < 4; ++j) {
                int row = rowbase + s*16 + l4*4 + j;
                int o = cs * N_PTS + row;
                val1[o] = b1[s*4+j];
                idx1[o] = i1[s*4+j];
                val2[o] = b2[s*4+j];
            }
    }
}

// ============================================================
// K2: merge 8 code-split partials; flag narrow-margin rows; histogram
// ============================================================
__global__ __launch_bounds__(256) void combine_kernel(const float* __restrict__ val1,
                                                      const int* __restrict__ idx1,
                                                      const float* __restrict__ val2,
                                                      int* __restrict__ ws_idx,
                                                      float* __restrict__ out_idxf,
                                                      int* __restrict__ fixcnt,
                                                      int* __restrict__ fixlist,
                                                      float* __restrict__ counts) {
    int row = blockIdx.x * 256 + threadIdx.x;
    float b1 = val1[row]; int i1 = idx1[row]; float b2 = val2[row];
#pragma unroll
    for (int c = 1; c < 8; ++c) {
        float ob1 = val1[c*N_PTS + row];
        int   oi1 = idx1[c*N_PTS + row];
        float ob2 = val2[c*N_PTS + row];
        float nb2 = fminf(fminf(b2, ob2), fmaxf(b1, ob1));
        if (ob1 < b1) { b1 = ob1; i1 = oi1; }   // splits ascend: ties keep lower idx
        b2 = nb2;
    }
    ws_idx[row]   = i1;
    out_idxf[row] = (float)i1;
    atomicAdd(&counts[i1], 1.0f);
    if (b2 - b1 < MARGIN_SCALED) {
        int p = atomicAdd(fixcnt, 1);
        if (p < 4096) fixlist[p] = row;
    }
}

// ============================================================
// K3: exact f32 recheck for flagged rows; fix histogram if changed
// ============================================================
__global__ __launch_bounds__(256) void fixup_kernel(const float* __restrict__ z,
                                                    const float* __restrict__ emb,
                                                    const float* __restrict__ enorm,
                                                    const int* __restrict__ fixcnt,
                                                    const int* __restrict__ fixlist,
                                                    int* __restrict__ ws_idx,
                                                    float* __restrict__ out_idxf,
                                                    float* __restrict__ counts) {
    __shared__ float zrow[64];
    __shared__ float rv[256];
    __shared__ int   ri[256];
    int cnt = *fixcnt; if (cnt > 4096) cnt = 4096;
    for (int g = blockIdx.x; g < cnt; g += 64) {
        int row = fixlist[g];
        __syncthreads();
        if (threadIdx.x < 64) zrow[threadIdx.x] = z[(size_t)row * DIMS + threadIdx.x];
        __syncthreads();
        float best = 3.4e38f; int bi = 0;
        for (int k = threadIdx.x; k < K_CODES; k += 256) {
            const float4* e4 = reinterpret_cast<const float4*>(emb + (size_t)k * DIMS);
            float s = 0.0f;
#pragma unroll
            for (int i = 0; i < 16; ++i) {
                float4 ev = e4[i];
                s = fmaf(zrow[i*4+0], ev.x, s);
                s = fmaf(zrow[i*4+1], ev.y, s);
                s = fmaf(zrow[i*4+2], ev.z, s);
                s = fmaf(zrow[i*4+3], ev.w, s);
            }
            float d = fmaf(-2.0f, s, enorm[k]);
            if (d < best) { best = d; bi = k; }
        }
        rv[threadIdx.x] = best; ri[threadIdx.x] = bi;
        __syncthreads();
        for (int off = 128; off > 0; off >>= 1) {
            if (threadIdx.x < off) {
                float ov = rv[threadIdx.x + off]; int oi = ri[threadIdx.x + off];
                if (ov < rv[threadIdx.x] || (ov == rv[threadIdx.x] && oi < ri[threadIdx.x])) {
                    rv[threadIdx.x] = ov; ri[threadIdx.x] = oi;
                }
            }
            __syncthreads();
        }
        if (threadIdx.x == 0) {
            int old = ws_idx[row];
            if (ri[0] != old) {
                atomicAdd(&counts[old], -1.0f);
                atomicAdd(&counts[ri[0]], 1.0f);
                ws_idx[row] = ri[0];
                out_idxf[row] = (float)ri[0];
            }
        }
    }
}

// ============================================================
// K4: single block: new_cluster_size + n + exclusive scan of counts
// ============================================================
__global__ __launch_bounds__(256) void scan_cs_kernel(const float* __restrict__ ema_cs,
                                                      const float* __restrict__ counts,
                                                      float* __restrict__ ncs_ws,
                                                      float* __restrict__ out_ncs,
                                                      float* __restrict__ nsum,
                                                      int* __restrict__ offsets) {
    __shared__ int excl[256];
    __shared__ int tot[256];
    __shared__ float fpart[256];
    const int t = threadIdx.x;
    const int base = t * 32;
    int loc[32];
    int run = 0;
    float fs = 0.0f;
#pragma unroll
    for (int i = 0; i < 32; ++i) {
        float c = counts[base + i];
        float v = fmaf(0.99f, ema_cs[base + i], 0.01f * c);
        ncs_ws[base + i] = v;
        out_ncs[base + i] = v;
        fs += v;
        loc[i] = run;
        run += (int)c;
    }
    tot[t] = run;
    fpart[t] = fs;
    __syncthreads();
    if (t == 0) {
        int r = 0;
        float f = 0.0f;
        for (int i = 0; i < 256; ++i) { excl[i] = r; r += tot[i]; f += fpart[i]; }
        nsum[0] = f;
    }
    __syncthreads();
    const int off = excl[t];
#pragma unroll
    for (int i = 0; i < 32; ++i) offsets[base + i] = off + loc[i];
}

// ============================================================
// K5: place point ids into code-sorted order (sorted/offsets in d_ws now)
// ============================================================
__global__ __launch_bounds__(256) void place_kernel(const int* __restrict__ idx,
                                                    const int* __restrict__ offsets,
                                                    int* __restrict__ cursor,
                                                    int* __restrict__ sorted) {
    int p = blockIdx.x * 256 + threadIdx.x;
    int k = idx[p];
    int pos = offsets[k] + atomicAdd(&cursor[k], 1);
    sorted[pos] = p;
}

// ============================================================
// K6: gather z_q, write z_q_st, loss (scratch in z_q region all dead by now)
// ============================================================
__global__ __launch_bounds__(256) void scatter_light(const float* __restrict__ z,
                                                     const float* __restrict__ emb,
                                                     const int* __restrict__ idx,
                                                     float* __restrict__ zq_out,
                                                     float* __restrict__ loss_accum) {
    const int tid = threadIdx.x;
    const int p = blockIdx.x * 64 + (tid >> 2);
    const int q = tid & 3;
    const int k = idx[p];

    const float4* zp = reinterpret_cast<const float4*>(z + (size_t)p * DIMS + q * 16);
    const float4* ep = reinterpret_cast<const float4*>(emb + (size_t)k * DIMS + q * 16);
    float4* op = reinterpret_cast<float4*>(zq_out + (size_t)p * DIMS + q * 16);

    float lsum = 0.0f;
#pragma unroll
    for (int i = 0; i < 4; ++i) {
        float4 zv = zp[i];
        float4 ev = ep[i];
        float4 t;
        t.x = ev.x - zv.x; t.y = ev.y - zv.y; t.z = ev.z - zv.z; t.w = ev.w - zv.w;
        lsum = fmaf(t.x, t.x, lsum); lsum = fmaf(t.y, t.y, lsum);
        lsum = fmaf(t.z, t.z, lsum); lsum = fmaf(t.w, t.w, lsum);
        float4 o;
        o.x = zv.x + t.x; o.y = zv.y + t.y; o.z = zv.z + t.z; o.w = zv.w + t.w;
        op[i] = o;
    }
#pragma unroll
    for (int o = 32; o > 0; o >>= 1) lsum += __shfl_down(lsum, o);
    if ((tid & 63) == 0) atomicAdd(loss_accum, lsum);
}

// ============================================================
// K7: dw (registers only) + EMA finalize fused. One wave per code.
// Runs last: loss_accum complete (stream order), nsum/offsets/sorted ready.
// ============================================================
__global__ __launch_bounds__(256) void dw_final(const float* __restrict__ z,
                                                const int* __restrict__ sorted,
                                                const int* __restrict__ offsets,
                                                const float* __restrict__ counts,
                                                const float* __restrict__ ema_emb,
                                                const float* __restrict__ ncs,
                                                const float* __restrict__ n_ptr,
                                                const float* __restrict__ loss_ptr,
                                                float* __restrict__ out_newemb,
                                                float* __restrict__ out_newema,
                                                float* __restrict__ out_loss) {
    const int w = threadIdx.x >> 6;
    const int lane = threadIdx.x & 63;
    const int k = blockIdx.x * 4 + w;
    const int start = offsets[k];
    const int cnt = (int)counts[k];
    float s = 0.0f;
    for (int i = 0; i < cnt; ++i) {
        int p = sorted[start + i];
        s += z[(size_t)p * DIMS + lane];
    }
    const float n = *n_ptr;
    const float cs = (ncs[k] + 1e-5f) / (n + (float)K_CODES * 1e-5f) * n;
    const float ne = fmaf(0.99f, ema_emb[(size_t)k * DIMS + lane], 0.01f * s);
    out_newema[(size_t)k * DIMS + lane] = ne;
    out_newemb[(size_t)k * DIMS + lane] = ne / cs;
    if (blockIdx.x == 0 && threadIdx.x == 0)
        out_loss[0] = 0.25f * (loss_ptr[0] / 2097152.0f);
}

extern "C" void kernel_launch(void* const* d_in, const int* in_sizes, int n_in,
                              void* d_out, int out_size, void* d_ws, size_t ws_size,
                              hipStream_t stream) {
    const float* z       = (const float*)d_in[0];
    const float* emb     = (const float*)d_in[1];
    const float* ema_cs  = (const float*)d_in[2];
    const float* ema_emb = (const float*)d_in[3];
    float* out = (float*)d_out;
    float* ws  = (float*)d_ws;

    float* counts  = ws + WS_COUNTS;
    int*   cursor  = (int*)(ws + WS_CURSOR);
    float* loss    = ws + WS_LOSS;
    float* nsum    = ws + WS_NSUM;
    int*   fixcnt  = (int*)(ws + WS_FIXCNT);
    float* ncs     = ws + WS_NCS;
    float* enorm   = ws + WS_ENORM;
    int*   idx     = (int*)(ws + WS_IDX);
    int*   sorted  = (int*)(ws + WS_SORTED);
    int*   offsets = (int*)(ws + WS_OFFSETS);

    float* ehi     = out + SC_EHI;
    float* elo     = out + SC_ELO;
    float* ensc    = out + SC_ENSC;
    float* val1    = out + SC_VAL1;
    int*   idx1    = (int*)(out + SC_IDX1);
    float* val2    = out + SC_VAL2;
    int*   fixlist = (int*)(out + SC_FIXLIST);

    hipMemsetAsync(d_ws, 0, WS_ZERO_BYTES, stream);

    esplit_kernel<<<K_CODES / 256, 256, 0, stream>>>(emb, (float4*)ehi, (float4*)elo, ensc, enorm);

    argmin_mfma<<<2048, 256, 0, stream>>>(z, (const char*)ehi, (const char*)elo, ensc,
                                          val1, idx1, val2);

    combine_kernel<<<N_PTS / 256, 256, 0, stream>>>(val1, idx1, val2, idx, out + OUT_IDX,
                                                    fixcnt, fixlist, counts);

    fixup_kernel<<<64, 256, 0, stream>>>(z, emb, enorm, fixcnt, fixlist, idx, out + OUT_IDX,
                                         counts);

    scan_cs_kernel<<<1, 256, 0, stream>>>(ema_cs, counts, ncs, out + OUT_NCS, nsum, offsets);

    place_kernel<<<N_PTS / 256, 256, 0, stream>>>(idx, offsets, cursor, sorted);

    scatter_light<<<N_PTS / 64, 256, 0, stream>>>(z, emb, idx, out + OUT_ZQ, loss);

    dw_final<<<K_CODES / 4, 256, 0, stream>>>(z, sorted, offsets, counts, ema_emb, ncs,
                                              nsum, loss,
                                              out + OUT_NEWEMB, out + OUT_NEWEMA,
                                              out + OUT_LOSS);
}

// Round 13
// 301.641 us; speedup vs baseline: 1.0236x; 1.0236x over previous
//
#include <hip/hip_runtime.h>

typedef _Float16 half8 __attribute__((ext_vector_type(8)));
typedef float f32x4 __attribute__((ext_vector_type(4)));

#define N_PTS   32768
#define DIMS    64
#define K_CODES 8192

// ---- d_out layout (floats, reference return order) ----
#define OUT_ZQ      0          // 32768*64
#define OUT_IDX     2097152    // 32768 (as float)
#define OUT_LOSS    2129920    // 1
#define OUT_NEWEMB  2129921    // 8192*64
#define OUT_NCS     2654209    // 8192
#define OUT_NEWEMA  2662401    // 8192*64

// ---- scratch inside the z_q region of d_out ----
// All consumed BEFORE scatter_light writes z_q.
#define SC_EHI      0          // 262144 floats
#define SC_ELO      262144     // 262144
#define SC_ENSC     524288     // 8192
#define SC_VAL1     532480     // 4*32768
#define SC_IDX1     794624     // 4*32768 (int)
#define SC_VAL2     1056768    // 4*32768
#define SC_FIXLIST  1318912    // 4096 (int)
// ends 1323008 < 2097152

// ---- d_ws layout (floats) ----
#define WS_COUNTS   0          // 8192
#define WS_CURSOR   8192       // 8192 (int)
#define WS_LOSS     16384
#define WS_NSUM     16385
#define WS_FIXCNT   16386      // int (+1 pad)
#define WS_ZERO_BYTES (16388u * 4u)
#define WS_NCS      16388      // 8192
#define WS_ENORM    24580      // 8192
#define WS_IDX      32772      // 32768 (int)
#define WS_SORTED   65540      // 32768 (int)
#define WS_OFFSETS  98308      // 8192 (int)

// r12 postmortem: MARGIN 16 flagged O(1000) rows -> fixup was the hidden
// ~100us tail kernel. Emulation error budget ~1 scaled; 4.0 keeps >4x safety.
#define MARGIN_SCALED 4.0f

__device__ inline void gld16(const void* g, void* l) {
    __builtin_amdgcn_global_load_lds((const __attribute__((address_space(1))) unsigned*)g,
                                     (__attribute__((address_space(3))) unsigned*)l, 16, 0, 0);
}
__device__ inline void gld4(const void* g, void* l) {
    __builtin_amdgcn_global_load_lds((const __attribute__((address_space(1))) unsigned*)g,
                                     (__attribute__((address_space(3))) unsigned*)l, 4, 0, 0);
}

// ============================================================
// K0: split codebook into f16 hi/lo (x256), 16B-chunk-swizzled; norms.
// ============================================================
__global__ __launch_bounds__(256) void esplit_kernel(const float* __restrict__ emb,
                                                     float4* __restrict__ ehi4,
                                                     float4* __restrict__ elo4,
                                                     float* __restrict__ ensc,
                                                     float* __restrict__ enorm) {
    int k = blockIdx.x * 256 + threadIdx.x;
    const float4* e4 = reinterpret_cast<const float4*>(emb + (size_t)k * DIMS);
    float vals[64];
    float sum = 0.0f;
#pragma unroll
    for (int i = 0; i < 16; ++i) {
        float4 v = e4[i];
        vals[i*4+0] = v.x; vals[i*4+1] = v.y; vals[i*4+2] = v.z; vals[i*4+3] = v.w;
        sum = fmaf(v.x, v.x, sum); sum = fmaf(v.y, v.y, sum);
        sum = fmaf(v.z, v.z, sum); sum = fmaf(v.w, v.w, sum);
    }
    enorm[k] = sum;
    ensc[k]  = 65536.0f * sum;
#pragma unroll
    for (int c = 0; c < 8; ++c) {
        union { _Float16 h[8]; float4 v; } uh, ul;
#pragma unroll
        for (int j = 0; j < 8; ++j) {
            float X = 256.0f * vals[c*8+j];
            _Float16 hh = (_Float16)X;
            uh.h[j] = hh;
            ul.h[j] = (_Float16)(X - (float)hh);
        }
        int cc = c ^ (k & 7);
        ehi4[(size_t)k*8 + cc] = uh.v;
        elo4[(size_t)k*8 + cc] = ul.v;
    }
}

// ============================================================
// K1: MFMA argmin -- r10 geometry restored (measured best: 111us).
// 2-subtile waves (32 rows/wave, 128 rows/block), 64-code chunks
// (4 tiles/chunk amortizes barriers; r12's 32-code chunks regressed),
// 4 code-splits, grid 1024. Plain __launch_bounds__(256): never force
// min-waves (r6/r8 spills); VGPR lands ~56, no spill.
// ============================================================
__global__ __launch_bounds__(256) void argmin_mfma(const float* __restrict__ z,
                                                   const char* __restrict__ ehi_g,
                                                   const char* __restrict__ elo_g,
                                                   const float* __restrict__ ensc_g,
                                                   float* __restrict__ val1,
                                                   int* __restrict__ idx1,
                                                   float* __restrict__ val2) {
    __shared__ __align__(16) char ebuf[2][2][8192];
    __shared__ float enb[2][64];

    const int tid = threadIdx.x;
    const int w   = tid >> 6;
    const int l   = tid & 63;
    const int l15 = l & 15;
    const int l4  = l >> 4;
    const int bid = blockIdx.x;
    const int rowbase = (bid >> 2) * 128 + w * 32;
    const int c0      = (bid & 3) * 2048;

    half8 ahi[2][2], alo[2][2];
#pragma unroll
    for (int s = 0; s < 2; ++s) {
        const float* zp = z + (size_t)(rowbase + s*16 + l15) * DIMS + l4 * 8;
#pragma unroll
        for (int ks = 0; ks < 2; ++ks) {
            float4 z0 = *reinterpret_cast<const float4*>(zp + ks*32);
            float4 z1 = *reinterpret_cast<const float4*>(zp + ks*32 + 4);
            float xv[8] = {z0.x, z0.y, z0.z, z0.w, z1.x, z1.y, z1.z, z1.w};
            half8 h, lo;
#pragma unroll
            for (int j = 0; j < 8; ++j) {
                float X = -512.0f * xv[j];
                _Float16 hh = (_Float16)X;
                h[j]  = hh;
                lo[j] = (_Float16)(X - (float)hh);
            }
            ahi[s][ks] = h; alo[s][ks] = lo;
        }
    }

    float b1[8], b2[8]; int i1[8];
#pragma unroll
    for (int r = 0; r < 8; ++r) { b1[r] = 3.4e38f; b2[r] = 3.4e38f; i1[r] = 0; }

    int rdoff[2];
#pragma unroll
    for (int ks = 0; ks < 2; ++ks)
        rdoff[ks] = l15 * 128 + (((ks*4 + l4) ^ (l15 & 7)) * 16);

    {
        const size_t gb = (size_t)c0 * 128;
        const char* sh = ehi_g + gb + tid*16;
        const char* sl = elo_g + gb + tid*16;
        char* dh = &ebuf[0][0][0] + w*1024;
        char* dl = &ebuf[0][1][0] + w*1024;
        gld16(sh,        dh);        gld16(sh + 4096, dh + 4096);
        gld16(sl,        dl);        gld16(sl + 4096, dl + 4096);
        if (w == 0) gld4(ensc_g + c0 + l, &enb[0][0]);
    }
    __syncthreads();

    int b = 0;
    for (int ch = 0; ch < 32; ++ch) {
        if (ch < 31) {
            const size_t gb = (size_t)(c0 + (ch+1)*64) * 128;
            const char* sh = ehi_g + gb + tid*16;
            const char* sl = elo_g + gb + tid*16;
            char* dh = &ebuf[b^1][0][0] + w*1024;
            char* dl = &ebuf[b^1][1][0] + w*1024;
            gld16(sh,        dh);        gld16(sh + 4096, dh + 4096);
            gld16(sl,        dl);        gld16(sl + 4096, dl + 4096);
            if (w == 0) gld4(ensc_g + c0 + (ch+1)*64 + l, &enb[b^1][0]);
        }
        const char* bhbase = &ebuf[b][0][0];
        const char* blbase = &ebuf[b][1][0];
#pragma unroll
        for (int t = 0; t < 4; ++t) {
            float en = enb[b][t*16 + l15];
            f32x4 envec = (f32x4){en, en, en, en};
            half8 bh[2], bl[2];
#pragma unroll
            for (int ks = 0; ks < 2; ++ks) {
                bh[ks] = *reinterpret_cast<const half8*>(bhbase + t*2048 + rdoff[ks]);
                bl[ks] = *reinterpret_cast<const half8*>(blbase + t*2048 + rdoff[ks]);
            }
            f32x4 acc[2];
            __builtin_amdgcn_s_setprio(1);
#pragma unroll
            for (int s = 0; s < 2; ++s)
                acc[s] = __builtin_amdgcn_mfma_f32_16x16x32_f16(ahi[s][0], bh[0], envec, 0, 0, 0);
#pragma unroll
            for (int s = 0; s < 2; ++s)
                acc[s] = __builtin_amdgcn_mfma_f32_16x16x32_f16(ahi[s][0], bl[0], acc[s], 0, 0, 0);
#pragma unroll
            for (int s = 0; s < 2; ++s)
                acc[s] = __builtin_amdgcn_mfma_f32_16x16x32_f16(alo[s][0], bh[0], acc[s], 0, 0, 0);
#pragma unroll
            for (int s = 0; s < 2; ++s)
                acc[s] = __builtin_amdgcn_mfma_f32_16x16x32_f16(ahi[s][1], bh[1], acc[s], 0, 0, 0);
#pragma unroll
            for (int s = 0; s < 2; ++s)
                acc[s] = __builtin_amdgcn_mfma_f32_16x16x32_f16(ahi[s][1], bl[1], acc[s], 0, 0, 0);
#pragma unroll
            for (int s = 0; s < 2; ++s)
                acc[s] = __builtin_amdgcn_mfma_f32_16x16x32_f16(alo[s][1], bh[1], acc[s], 0, 0, 0);
            __builtin_amdgcn_s_setprio(0);

            const int code = c0 + ch*64 + t*16 + l15;
#pragma unroll
            for (int s = 0; s < 2; ++s) {
#pragma unroll
                for (int j = 0; j < 4; ++j) {
                    const int r = s*4 + j;
                    float v = acc[s][j];
                    float nb2;
                    asm("v_med3_f32 %0, %1, %2, %3"
                        : "=v"(nb2) : "v"(b1[r]), "v"(b2[r]), "v"(v));
                    b2[r] = nb2;
                    bool c = v < b1[r];
                    b1[r] = c ? v : b1[r];
                    i1[r] = c ? code : i1[r];
                }
            }
        }
        __syncthreads();
        b ^= 1;
    }

#pragma unroll
    for (int m = 1; m < 16; m <<= 1) {
#pragma unroll
        for (int r = 0; r < 8; ++r) {
            float ob1 = __shfl_xor(b1[r], m, 64);
            int   oi1 = __shfl_xor(i1[r], m, 64);
            float ob2 = __shfl_xor(b2[r], m, 64);
            float nb2 = fminf(fminf(b2[r], ob2), fmaxf(b1[r], ob1));
            bool take = (ob1 < b1[r]) || (ob1 == b1[r] && oi1 < i1[r]);
            b1[r] = take ? ob1 : b1[r];
            i1[r] = take ? oi1 : i1[r];
            b2[r] = nb2;
        }
    }
    if (l15 == 0) {
        const int cs = bid & 3;
#pragma unroll
        for (int s = 0; s < 2; ++s)
#pragma unroll
            for (int j = 0; j < 4; ++j) {
                int row = rowbase + s*16 + l4*4 + j;
                int o = cs * N_PTS + row;
                val1[o] = b1[s*4+j];
                idx1[o] = i1[s*4+j];
                val2[o] = b2[s*4+j];
            }
    }
}

// ============================================================
// K2: merge 4 code-split partials; flag narrow-margin rows; histogram
// ============================================================
__global__ __launch_bounds__(256) void combine_kernel(const float* __restrict__ val1,
                                                      const int* __restrict__ idx1,
                                                      const float* __restrict__ val2,
                                                      int* __restrict__ ws_idx,
                                                      float* __restrict__ out_idxf,
                                                      int* __restrict__ fixcnt,
                                                      int* __restrict__ fixlist,
                                                      float* __restrict__ counts) {
    int row = blockIdx.x * 256 + threadIdx.x;
    float b1 = val1[row]; int i1 = idx1[row]; float b2 = val2[row];
#pragma unroll
    for (int c = 1; c < 4; ++c) {
        float ob1 = val1[c*N_PTS + row];
        int   oi1 = idx1[c*N_PTS + row];
        float ob2 = val2[c*N_PTS + row];
        float nb2 = fminf(fminf(b2, ob2), fmaxf(b1, ob1));
        if (ob1 < b1) { b1 = ob1; i1 = oi1; }   // splits ascend: ties keep lower idx
        b2 = nb2;
    }
    ws_idx[row]   = i1;
    out_idxf[row] = (float)i1;
    atomicAdd(&counts[i1], 1.0f);
    if (b2 - b1 < MARGIN_SCALED) {
        int p = atomicAdd(fixcnt, 1);
        if (p < 4096) fixlist[p] = row;
    }
}

// ============================================================
// K3: exact f32 recheck. r12 postmortem: 64-block grid serialized rows
// (cnt/64 sequential rows x ~1.7us = the hidden ~100us tail kernel).
// Now 4096 blocks -> one row per block in parallel; wall ~= one-row time.
// ============================================================
__global__ __launch_bounds__(256) void fixup_kernel(const float* __restrict__ z,
                                                    const float* __restrict__ emb,
                                                    const float* __restrict__ enorm,
                                                    const int* __restrict__ fixcnt,
                                                    const int* __restrict__ fixlist,
                                                    int* __restrict__ ws_idx,
                                                    float* __restrict__ out_idxf,
                                                    float* __restrict__ counts) {
    __shared__ float zrow[64];
    __shared__ float rv[256];
    __shared__ int   ri[256];
    int cnt = *fixcnt; if (cnt > 4096) cnt = 4096;
    for (int g = blockIdx.x; g < cnt; g += 4096) {
        int row = fixlist[g];
        __syncthreads();
        if (threadIdx.x < 64) zrow[threadIdx.x] = z[(size_t)row * DIMS + threadIdx.x];
        __syncthreads();
        float best = 3.4e38f; int bi = 0;
        for (int k = threadIdx.x; k < K_CODES; k += 256) {
            const float4* e4 = reinterpret_cast<const float4*>(emb + (size_t)k * DIMS);
            float s = 0.0f;
#pragma unroll
            for (int i = 0; i < 16; ++i) {
                float4 ev = e4[i];
                s = fmaf(zrow[i*4+0], ev.x, s);
                s = fmaf(zrow[i*4+1], ev.y, s);
                s = fmaf(zrow[i*4+2], ev.z, s);
                s = fmaf(zrow[i*4+3], ev.w, s);
            }
            float d = fmaf(-2.0f, s, enorm[k]);
            if (d < best) { best = d; bi = k; }
        }
        rv[threadIdx.x] = best; ri[threadIdx.x] = bi;
        __syncthreads();
        for (int off = 128; off > 0; off >>= 1) {
            if (threadIdx.x < off) {
                float ov = rv[threadIdx.x + off]; int oi = ri[threadIdx.x + off];
                if (ov < rv[threadIdx.x] || (ov == rv[threadIdx.x] && oi < ri[threadIdx.x])) {
                    rv[threadIdx.x] = ov; ri[threadIdx.x] = oi;
                }
            }
            __syncthreads();
        }
        if (threadIdx.x == 0) {
            int old = ws_idx[row];
            if (ri[0] != old) {
                atomicAdd(&counts[old], -1.0f);
                atomicAdd(&counts[ri[0]], 1.0f);
                ws_idx[row] = ri[0];
                out_idxf[row] = (float)ri[0];
            }
        }
    }
}

// ============================================================
// K4: single block: new_cluster_size + n + exclusive scan of counts
// ============================================================
__global__ __launch_bounds__(256) void scan_cs_kernel(const float* __restrict__ ema_cs,
                                                      const float* __restrict__ counts,
                                                      float* __restrict__ ncs_ws,
                                                      float* __restrict__ out_ncs,
                                                      float* __restrict__ nsum,
                                                      int* __restrict__ offsets) {
    __shared__ int excl[256];
    __shared__ int tot[256];
    __shared__ float fpart[256];
    const int t = threadIdx.x;
    const int base = t * 32;
    int loc[32];
    int run = 0;
    float fs = 0.0f;
#pragma unroll
    for (int i = 0; i < 32; ++i) {
        float c = counts[base + i];
        float v = fmaf(0.99f, ema_cs[base + i], 0.01f * c);
        ncs_ws[base + i] = v;
        out_ncs[base + i] = v;
        fs += v;
        loc[i] = run;
        run += (int)c;
    }
    tot[t] = run;
    fpart[t] = fs;
    __syncthreads();
    if (t == 0) {
        int r = 0;
        float f = 0.0f;
        for (int i = 0; i < 256; ++i) { excl[i] = r; r += tot[i]; f += fpart[i]; }
        nsum[0] = f;
    }
    __syncthreads();
    const int off = excl[t];
#pragma unroll
    for (int i = 0; i < 32; ++i) offsets[base + i] = off + loc[i];
}

// ============================================================
// K5: place point ids into code-sorted order (sorted/offsets in d_ws)
// ============================================================
__global__ __launch_bounds__(256) void place_kernel(const int* __restrict__ idx,
                                                    const int* __restrict__ offsets,
                                                    int* __restrict__ cursor,
                                                    int* __restrict__ sorted) {
    int p = blockIdx.x * 256 + threadIdx.x;
    int k = idx[p];
    int pos = offsets[k] + atomicAdd(&cursor[k], 1);
    sorted[pos] = p;
}

// ============================================================
// K6: gather z_q, write z_q_st, loss
// ============================================================
__global__ __launch_bounds__(256) void scatter_light(const float* __restrict__ z,
                                                     const float* __restrict__ emb,
                                                     const int* __restrict__ idx,
                                                     float* __restrict__ zq_out,
                                                     float* __restrict__ loss_accum) {
    const int tid = threadIdx.x;
    const int p = blockIdx.x * 64 + (tid >> 2);
    const int q = tid & 3;
    const int k = idx[p];

    const float4* zp = reinterpret_cast<const float4*>(z + (size_t)p * DIMS + q * 16);
    const float4* ep = reinterpret_cast<const float4*>(emb + (size_t)k * DIMS + q * 16);
    float4* op = reinterpret_cast<float4*>(zq_out + (size_t)p * DIMS + q * 16);

    float lsum = 0.0f;
#pragma unroll
    for (int i = 0; i < 4; ++i) {
        float4 zv = zp[i];
        float4 ev = ep[i];
        float4 t;
        t.x = ev.x - zv.x; t.y = ev.y - zv.y; t.z = ev.z - zv.z; t.w = ev.w - zv.w;
        lsum = fmaf(t.x, t.x, lsum); lsum = fmaf(t.y, t.y, lsum);
        lsum = fmaf(t.z, t.z, lsum); lsum = fmaf(t.w, t.w, lsum);
        float4 o;
        o.x = zv.x + t.x; o.y = zv.y + t.y; o.z = zv.z + t.z; o.w = zv.w + t.w;
        op[i] = o;
    }
#pragma unroll
    for (int o = 32; o > 0; o >>= 1) lsum += __shfl_down(lsum, o);
    if ((tid & 63) == 0) atomicAdd(loss_accum, lsum);
}

// ============================================================
// K7: dw (registers only) + EMA finalize fused. One wave per code.
// ============================================================
__global__ __launch_bounds__(256) void dw_final(const float* __restrict__ z,
                                                const int* __restrict__ sorted,
                                                const int* __restrict__ offsets,
                                                const float* __restrict__ counts,
                                                const float* __restrict__ ema_emb,
                                                const float* __restrict__ ncs,
                                                const float* __restrict__ n_ptr,
                                                const float* __restrict__ loss_ptr,
                                                float* __restrict__ out_newemb,
                                                float* __restrict__ out_newema,
                                                float* __restrict__ out_loss) {
    const int w = threadIdx.x >> 6;
    const int lane = threadIdx.x & 63;
    const int k = blockIdx.x * 4 + w;
    const int start = offsets[k];
    const int cnt = (int)counts[k];
    float s = 0.0f;
    for (int i = 0; i < cnt; ++i) {
        int p = sorted[start + i];
        s += z[(size_t)p * DIMS + lane];
    }
    const float n = *n_ptr;
    const float cs = (ncs[k] + 1e-5f) / (n + (float)K_CODES * 1e-5f) * n;
    const float ne = fmaf(0.99f, ema_emb[(size_t)k * DIMS + lane], 0.01f * s);
    out_newema[(size_t)k * DIMS + lane] = ne;
    out_newemb[(size_t)k * DIMS + lane] = ne / cs;
    if (blockIdx.x == 0 && threadIdx.x == 0)
        out_loss[0] = 0.25f * (loss_ptr[0] / 2097152.0f);
}

extern "C" void kernel_launch(void* const* d_in, const int* in_sizes, int n_in,
                              void* d_out, int out_size, void* d_ws, size_t ws_size,
                              hipStream_t stream) {
    const float* z       = (const float*)d_in[0];
    const float* emb     = (const float*)d_in[1];
    const float* ema_cs  = (const float*)d_in[2];
    const float* ema_emb = (const float*)d_in[3];
    float* out = (float*)d_out;
    float* ws  = (float*)d_ws;

    float* counts  = ws + WS_COUNTS;
    int*   cursor  = (int*)(ws + WS_CURSOR);
    float* loss    = ws + WS_LOSS;
    float* nsum    = ws + WS_NSUM;
    int*   fixcnt  = (int*)(ws + WS_FIXCNT);
    float* ncs     = ws + WS_NCS;
    float* enorm   = ws + WS_ENORM;
    int*   idx     = (int*)(ws + WS_IDX);
    int*   sorted  = (int*)(ws + WS_SORTED);
    int*   offsets = (int*)(ws + WS_OFFSETS);

    float* ehi     = out + SC_EHI;
    float* elo     = out + SC_ELO;
    float* ensc    = out + SC_ENSC;
    float* val1    = out + SC_VAL1;
    int*   idx1    = (int*)(out + SC_IDX1);
    float* val2    = out + SC_VAL2;
    int*   fixlist = (int*)(out + SC_FIXLIST);

    hipMemsetAsync(d_ws, 0, WS_ZERO_BYTES, stream);

    esplit_kernel<<<K_CODES / 256, 256, 0, stream>>>(emb, (float4*)ehi, (float4*)elo, ensc, enorm);

    argmin_mfma<<<1024, 256, 0, stream>>>(z, (const char*)ehi, (const char*)elo, ensc,
                                          val1, idx1, val2);

    combine_kernel<<<N_PTS / 256, 256, 0, stream>>>(val1, idx1, val2, idx, out + OUT_IDX,
                                                    fixcnt, fixlist, counts);

    fixup_kernel<<<4096, 256, 0, stream>>>(z, emb, enorm, fixcnt, fixlist, idx, out + OUT_IDX,
                                           counts);

    scan_cs_kernel<<<1, 256, 0, stream>>>(ema_cs, counts, ncs, out + OUT_NCS, nsum, offsets);

    place_kernel<<<N_PTS / 256, 256, 0, stream>>>(idx, offsets, cursor, sorted);

    scatter_light<<<N_PTS / 64, 256, 0, stream>>>(z, emb, idx, out + OUT_ZQ, loss);

    dw_final<<<K_CODES / 4, 256, 0, stream>>>(z, sorted, offsets, counts, ema_emb, ncs,
                                              nsum, loss,
                                              out + OUT_NEWEMB, out + OUT_NEWEMA,
                                              out + OUT_LOSS);
}